// Round 4
// baseline (3927.424 us; speedup 1.0000x reference)
//
#include <hip/hip_runtime.h>
#include <hip/hip_fp16.h>

// 2-layer LSTM, B=256 T=512 I=32 H=256.
// 16 groups x 16 batches, 6 wgs/group (2 L0 + 4 L1), 512 thr (8 waves).
// Wave = 16 units x 4 gates x 16 batches, weights register-resident.
// L1 split by K: A-wave (Wih1 * h0) + B-wave (Whh1 * h1) pair, partial-acc
// exchange via LDS. h transported fp16 via MALL (sc0 sc1) with a phase tag
// in the fp16 LSB: slot=(t)&1, tagbit=((t)>>1)&1 distinguishes 4 consecutive
// steps; consumers spin on DATA (no flags, no producer drain). L0 throttled
// by per-L1-wg progress byte to bound skew <= 2 (ABA-safe in 4-phase window).

#define NGRP 16
#define GB   16
#define NTH  512
#define HH   256
#define TT   512
#define II   32

typedef _Float16 f16x8 __attribute__((ext_vector_type(8)));
typedef float    f32x4 __attribute__((ext_vector_type(4)));

__device__ __forceinline__ f16x8 cvt8(const float* p) {
  const float4 a = *(const float4*)p;
  const float4 b = *(const float4*)(p + 4);
  f16x8 r;
  r[0]=(_Float16)a.x; r[1]=(_Float16)a.y; r[2]=(_Float16)a.z; r[3]=(_Float16)a.w;
  r[4]=(_Float16)b.x; r[5]=(_Float16)b.y; r[6]=(_Float16)b.z; r[7]=(_Float16)b.w;
  return r;
}

__device__ __forceinline__ float sigm(float x){ return 1.f/(1.f + __expf(-x)); }
__device__ __forceinline__ float tanh_(float x){ return 1.f - 2.f/(1.f + __expf(2.f*x)); }

// ---- MALL-coherent (L2-bypass) primitives ----
__device__ __forceinline__ uint4 load16_sv(unsigned voff, const void* base) {
  uint4 r;
  asm volatile("global_load_dwordx4 %0, %1, %2 sc0 sc1"
               : "=v"(r) : "v"(voff), "s"(base) : "memory");
  return r;
}
__device__ __forceinline__ void store2_sv(unsigned voff, unsigned v, void* base) {
  asm volatile("global_store_short %0, %1, %2 sc0 sc1"
               :: "v"(voff), "v"(v), "s"(base) : "memory");
}
__device__ __forceinline__ void store1_sc(void* p, unsigned v) {
  asm volatile("global_store_byte %0, %1, off sc0 sc1"
               :: "v"(p), "v"(v) : "memory");
}
__device__ __forceinline__ unsigned load4_sc(const void* p) {
  unsigned r;
  asm volatile("global_load_dword %0, %1, off sc0 sc1\n\ts_waitcnt vmcnt(0)"
               : "=v"(r) : "v"(p) : "memory");
  return r;
}

__global__ void init_ws(uint4* p, int n) {
  int i = blockIdx.x * blockDim.x + threadIdx.x;
  if (i < n) {
    // h region: fp16 pattern 0x0001 (tag=1, tiny denormal) -> never matches
    // the first real tags (0); prog region (last 4 uint4): zeros.
    uint4 v = (i < 32768) ? make_uint4(0x00010001u,0x00010001u,0x00010001u,0x00010001u)
                          : make_uint4(0u,0u,0u,0u);
    p[i] = v;
  }
}

__global__ __launch_bounds__(NTH, 1) void lstm_kernel(
    const float* __restrict__ M,
    const float* __restrict__ Wih0, const float* __restrict__ Whh0,
    const float* __restrict__ bih0, const float* __restrict__ bhh0,
    const float* __restrict__ Wih1, const float* __restrict__ Whh1,
    const float* __restrict__ bih1, const float* __restrict__ bhh1,
    float* __restrict__ out, char* __restrict__ ws)
{
  __shared__ __align__(16) float xch[4][4][64][4];   // [pair][gate][lane][4] = 16KB

  const int tid  = threadIdx.x;
  const int lane = tid & 63;
  const int wv   = tid >> 6;             // wave 0..7
  const int bid  = blockIdx.x;
  const int x    = bid & 7;              // XCD (heuristic)
  const int s    = bid >> 3;             // 0..11
  const int g    = x * 2 + (s >= 6);     // group 0..15
  const int r    = (s >= 6) ? s - 6 : s; // role wg 0..5
  const bool isL0 = (r < 2);
  const int pr   = wv >> 1;              // L1 pair 0..3
  const int role = wv & 1;               // 0=A (Wih1*h0), 1=B (Whh1*h1)
  const int ut   = isL0 ? (r * 8 + wv) : ((r - 2) * 4 + pr);  // unit-tile 0..15

  const int col16 = lane & 15;
  const int ko8   = (lane >> 4) << 3;
  const int unit  = ut * 16 + col16;

  char* hg = ws;                                   // h0: [2][16][16][256] f16 =256KB
  char* h1g = ws + 262144;                         // h1: same
  unsigned char* prog = (unsigned char*)(ws + 524288);  // [16 g][4 L1wg] bytes

  // ---- register-resident weights: 4 gates x 16 units ----
  f16x8 W0[4][8], WI[4];
  float bias[4];
  #pragma unroll
  for (int q = 0; q < 4; ++q) {
    const int grow = q * HH + unit;
    if (isL0) {
      #pragma unroll
      for (int kt = 0; kt < 8; ++kt)
        W0[q][kt] = cvt8(Whh0 + (size_t)grow * HH + kt * 32 + ko8);
      WI[q]   = cvt8(Wih0 + grow * II + ko8);
      bias[q] = bih0[grow] + bhh0[grow];
    } else if (role == 0) {
      #pragma unroll
      for (int kt = 0; kt < 8; ++kt)
        W0[q][kt] = cvt8(Wih1 + (size_t)grow * HH + kt * 32 + ko8);
      bias[q] = bih1[grow] + bhh1[grow];
    } else {
      #pragma unroll
      for (int kt = 0; kt < 8; ++kt)
        W0[q][kt] = cvt8(Whh1 + (size_t)grow * HH + kt * 32 + ko8);
      bias[q] = 0.f;
    }
  }

  // precomputed byte offsets (within one h slot)
  unsigned rvoff[8], wvoff[4];
  #pragma unroll
  for (int kt = 0; kt < 8; ++kt)
    rvoff[kt] = ((unsigned)(g * GB + col16) << 9) + (kt << 6) + ((lane >> 4) << 4);
  #pragma unroll
  for (int rr = 0; rr < 4; ++rr)
    wvoff[rr] = ((unsigned)(g * GB + ((lane >> 4) << 2) + rr) << 9) + ((unsigned)unit << 1);

  float c[4] = {0.f, 0.f, 0.f, 0.f};
  const int pstart = isL0 ? 0 : 1;
  const int pend   = isL0 ? (TT - 1) : TT;

  for (int p = pstart; p <= pend; ++p) {
    f32x4 acc[4];
    #pragma unroll
    for (int q = 0; q < 4; ++q) acc[q] = (f32x4){bias[q], bias[q], bias[q], bias[q]};

    uint4 v[8];
    if (isL0) {
      // M input (plain cached loads; L2-local per XCD)
      const float* mp = M + ((size_t)(g * GB + col16) * TT + p) * II + ko8;
      const float4 mA = *(const float4*)mp, mB = *(const float4*)(mp + 4);

      // throttle: bound run-ahead over slowest L1 wg of this group (skew<=2)
      if (p >= 2) {
        const unsigned char tgt = (unsigned char)(p - 1);
        const unsigned char* pa = prog + g * 4;
        while (true) {
          unsigned d = load4_sc(pa);
          int ok = ((int)(signed char)(unsigned char)((d & 0xFF) - tgt) >= 0)
                 & ((int)(signed char)(unsigned char)(((d >> 8) & 0xFF) - tgt) >= 0)
                 & ((int)(signed char)(unsigned char)(((d >> 16) & 0xFF) - tgt) >= 0)
                 & ((int)(signed char)(unsigned char)(((d >> 24) & 0xFF) - tgt) >= 0);
          if (ok) break;
        }
      }

      f16x8 am;
      am[0]=(_Float16)mA.x; am[1]=(_Float16)mA.y; am[2]=(_Float16)mA.z; am[3]=(_Float16)mA.w;
      am[4]=(_Float16)mB.x; am[5]=(_Float16)mB.y; am[6]=(_Float16)mB.z; am[7]=(_Float16)mB.w;
      #pragma unroll
      for (int q = 0; q < 4; ++q)
        acc[q] = __builtin_amdgcn_mfma_f32_16x16x32_f16(am, WI[q], acc[q], 0, 0, 0);

      if (p >= 1) {
        // spin-load h0[p-1] until all tags match
        const char* rbase = hg + (((p - 1) & 1) ? 131072 : 0);
        const unsigned pat = (((p - 1) >> 1) & 1) ? 0x00010001u : 0u;
        while (true) {
          #pragma unroll
          for (int kt = 0; kt < 8; ++kt) v[kt] = load16_sv(rvoff[kt], rbase);
          asm volatile("s_waitcnt vmcnt(0)" ::: "memory");
          __builtin_amdgcn_sched_barrier(0);
          unsigned ok = 1u;
          #pragma unroll
          for (int kt = 0; kt < 8; ++kt) {
            ok &= (unsigned)((v[kt].x & 0x00010001u) == pat);
            ok &= (unsigned)((v[kt].y & 0x00010001u) == pat);
            ok &= (unsigned)((v[kt].z & 0x00010001u) == pat);
            ok &= (unsigned)((v[kt].w & 0x00010001u) == pat);
          }
          if (__all((int)ok)) break;
        }
        #pragma unroll
        for (int kt = 0; kt < 8; ++kt) {
          const f16x8 a = __builtin_bit_cast(f16x8, v[kt]);
          #pragma unroll
          for (int q = 0; q < 4; ++q)
            acc[q] = __builtin_amdgcn_mfma_f32_16x16x32_f16(a, W0[q][kt], acc[q], 0, 0, 0);
        }
      }

      // elementwise + tagged h0[p] store (fire-and-forget)
      char* wbase = hg + ((p & 1) ? 131072 : 0);
      const unsigned wtag = (unsigned)((p >> 1) & 1);
      #pragma unroll
      for (int rr = 0; rr < 4; ++rr) {
        const float iv = sigm(acc[0][rr]), fv = sigm(acc[1][rr]);
        const float gv = tanh_(acc[2][rr]), ov = sigm(acc[3][rr]);
        c[rr] = fv * c[rr] + iv * gv;
        const float h = ov * tanh_(c[rr]);
        unsigned short hb = __builtin_bit_cast(unsigned short, (_Float16)h);
        hb = (unsigned short)((hb & 0xFFFEu) | wtag);
        store2_sv(wvoff[rr], (unsigned)hb, wbase);
      }
    } else {
      // ---- L1: phase p computes h1[p-1] ----
      if (role == 0) {
        // A: Wih1 * h0[p-1]
        const char* rbase = hg + (((p - 1) & 1) ? 131072 : 0);
        const unsigned pat = (((p - 1) >> 1) & 1) ? 0x00010001u : 0u;
        while (true) {
          #pragma unroll
          for (int kt = 0; kt < 8; ++kt) v[kt] = load16_sv(rvoff[kt], rbase);
          asm volatile("s_waitcnt vmcnt(0)" ::: "memory");
          __builtin_amdgcn_sched_barrier(0);
          unsigned ok = 1u;
          #pragma unroll
          for (int kt = 0; kt < 8; ++kt) {
            ok &= (unsigned)((v[kt].x & 0x00010001u) == pat);
            ok &= (unsigned)((v[kt].y & 0x00010001u) == pat);
            ok &= (unsigned)((v[kt].z & 0x00010001u) == pat);
            ok &= (unsigned)((v[kt].w & 0x00010001u) == pat);
          }
          if (__all((int)ok)) break;
        }
        #pragma unroll
        for (int kt = 0; kt < 8; ++kt) {
          const f16x8 a = __builtin_bit_cast(f16x8, v[kt]);
          #pragma unroll
          for (int q = 0; q < 4; ++q)
            acc[q] = __builtin_amdgcn_mfma_f32_16x16x32_f16(a, W0[q][kt], acc[q], 0, 0, 0);
        }
      } else if (p >= 2) {
        // B: Whh1 * h1[p-2]
        const char* rbase = h1g + (((p - 2) & 1) ? 131072 : 0);
        const unsigned pat = (((p - 2) >> 1) & 1) ? 0x00010001u : 0u;
        while (true) {
          #pragma unroll
          for (int kt = 0; kt < 8; ++kt) v[kt] = load16_sv(rvoff[kt], rbase);
          asm volatile("s_waitcnt vmcnt(0)" ::: "memory");
          __builtin_amdgcn_sched_barrier(0);
          unsigned ok = 1u;
          #pragma unroll
          for (int kt = 0; kt < 8; ++kt) {
            ok &= (unsigned)((v[kt].x & 0x00010001u) == pat);
            ok &= (unsigned)((v[kt].y & 0x00010001u) == pat);
            ok &= (unsigned)((v[kt].z & 0x00010001u) == pat);
            ok &= (unsigned)((v[kt].w & 0x00010001u) == pat);
          }
          if (__all((int)ok)) break;
        }
        #pragma unroll
        for (int kt = 0; kt < 8; ++kt) {
          const f16x8 a = __builtin_bit_cast(f16x8, v[kt]);
          #pragma unroll
          for (int q = 0; q < 4; ++q)
            acc[q] = __builtin_amdgcn_mfma_f32_16x16x32_f16(a, W0[q][kt], acc[q], 0, 0, 0);
        }
      }

      // exchange B -> A partials via LDS
      if (role == 1) {
        #pragma unroll
        for (int q = 0; q < 4; ++q)
          *(f32x4*)&xch[pr][q][lane][0] = acc[q];
      }
      __syncthreads();
      if (tid == 0)
        store1_sc(prog + g * 4 + (r - 2), (unsigned)(p & 0xFF));  // wg done reading
      if (role == 0) {
        #pragma unroll
        for (int q = 0; q < 4; ++q) {
          const f32x4 pb = *(const f32x4*)&xch[pr][q][lane][0];
          acc[q][0]+=pb[0]; acc[q][1]+=pb[1]; acc[q][2]+=pb[2]; acc[q][3]+=pb[3];
        }
        char* wbase = h1g + (((p - 1) & 1) ? 131072 : 0);
        const unsigned wtag = (unsigned)(((p - 1) >> 1) & 1);
        #pragma unroll
        for (int rr = 0; rr < 4; ++rr) {
          const float iv = sigm(acc[0][rr]), fv = sigm(acc[1][rr]);
          const float gv = tanh_(acc[2][rr]), ov = sigm(acc[3][rr]);
          c[rr] = fv * c[rr] + iv * gv;
          const float h = ov * tanh_(c[rr]);
          if (p < TT) {
            unsigned short hb = __builtin_bit_cast(unsigned short, (_Float16)h);
            hb = (unsigned short)((hb & 0xFFFEu) | wtag);
            store2_sv(wvoff[rr], (unsigned)hb, wbase);
          } else {
            const int b = ((lane >> 4) << 2) + rr;
            out[(size_t)(g * GB + b) * HH + unit] = h;   // final h1[T-1]
          }
        }
      }
      __syncthreads();   // protect xch reuse next phase
    }
  }
}

extern "C" void kernel_launch(void* const* d_in, const int* in_sizes, int n_in,
                              void* d_out, int out_size, void* d_ws, size_t ws_size,
                              hipStream_t stream) {
  (void)in_sizes; (void)n_in; (void)out_size;
  if (ws_size < 524800) return;   // 512KB h slots + prog bytes

  const float* M    = (const float*)d_in[0];
  const float* Wih0 = (const float*)d_in[1];
  const float* Whh0 = (const float*)d_in[2];
  const float* bih0 = (const float*)d_in[3];
  const float* bhh0 = (const float*)d_in[4];
  const float* Wih1 = (const float*)d_in[5];
  const float* Whh1 = (const float*)d_in[6];
  const float* bih1 = (const float*)d_in[7];
  const float* bhh1 = (const float*)d_in[8];

  const int nz = 32772;            // 512KB pattern + 64B prog
  init_ws<<<(nz + 255) / 256, 256, 0, stream>>>((uint4*)d_ws, nz);
  lstm_kernel<<<96, NTH, 0, stream>>>(M, Wih0, Whh0, bih0, bhh0,
                                      Wih1, Whh1, bih1, bhh1,
                                      (float*)d_out, (char*)d_ws);
}

// Round 7
// 2969.043 us; speedup vs baseline: 1.3228x; 1.3228x over previous
//
#include <hip/hip_runtime.h>
#include <hip/hip_fp16.h>

// 2-layer LSTM B=256 T=512 I=32 H=256.
// 8 groups x 32 batches x 16 wgs (512 thr, 8 waves). Weights register-resident.
// Waves: 0,1=L0 (batch halves); 2,3=L1-A (Wih1*h0); 4,5=L1-B (Whh1*h1);
// 6,7 stage-only. All 4 gates per lane -> elementwise fully in-register.
// h transported fp16 via MALL (sc0 sc1) with 1-bit lap tag in the fp16 LSB;
// consumers spin-load DIRECTLY in MFMA A-frag layout (no flags, no drains).
// 2-slot rings; lockstep is structural (staging p needs all stores of p-1).
// Barriers: raw s_barrier + lgkmcnt only (VMEM stores stay fire-and-forget).

#define TT 512
#define HH 256

typedef _Float16 f16x8 __attribute__((ext_vector_type(8)));
typedef float    f32x4 __attribute__((ext_vector_type(4)));
typedef unsigned u32x4 __attribute__((ext_vector_type(4)));

__device__ __forceinline__ f16x8 cvt8(const float* p) {
  const float4 a = *(const float4*)p;
  const float4 b = *(const float4*)(p + 4);
  f16x8 r;
  r[0]=(_Float16)a.x; r[1]=(_Float16)a.y; r[2]=(_Float16)a.z; r[3]=(_Float16)a.w;
  r[4]=(_Float16)b.x; r[5]=(_Float16)b.y; r[6]=(_Float16)b.z; r[7]=(_Float16)b.w;
  return r;
}
__device__ __forceinline__ float sigm(float x){ return 1.f/(1.f + __expf(-x)); }
__device__ __forceinline__ float tanh_(float x){ return 1.f - 2.f/(1.f + __expf(2.f*x)); }

// ---- MALL-coherent (L2-bypass) primitives ----
__device__ __forceinline__ u32x4 ld16_sv(unsigned voff, const void* base) {
  u32x4 r;
  asm volatile("global_load_dwordx4 %0, %1, %2 sc0 sc1"
               : "=v"(r) : "v"(voff), "s"(base) : "memory");
  return r;
}
__device__ __forceinline__ void st2_sv(unsigned voff, unsigned v, void* base) {
  asm volatile("global_store_short %0, %1, %2 sc0 sc1"
               :: "v"(voff), "v"(v), "s"(base) : "memory");
}
__device__ __forceinline__ void wvm0() {
  asm volatile("s_waitcnt vmcnt(0)" ::: "memory");
  __builtin_amdgcn_sched_barrier(0);
}
__device__ __forceinline__ void barrier_lds() {   // no vmcnt drain
  __builtin_amdgcn_sched_barrier(0);
  asm volatile("s_waitcnt lgkmcnt(0)" ::: "memory");
  __builtin_amdgcn_s_barrier();
  __builtin_amdgcn_sched_barrier(0);
}
// lap tag of step t (valid for t >= -2): 0,0,1,1,0,0,...
__device__ __forceinline__ unsigned tg(int t){ return ((unsigned)(t + 4) >> 1) & 1u; }

__global__ void init_ws(uint4* p, int n) {
  int i = blockIdx.x * blockDim.x + threadIdx.x;
  if (i < n) p[i] = make_uint4(0x00010001u,0x00010001u,0x00010001u,0x00010001u);
}

__global__ __launch_bounds__(512) void lstm_pipe(
    const float* __restrict__ M,
    const float* __restrict__ Wih0, const float* __restrict__ Whh0,
    const float* __restrict__ bih0, const float* __restrict__ bhh0,
    const float* __restrict__ Wih1, const float* __restrict__ Whh1,
    const float* __restrict__ bih1, const float* __restrict__ bhh1,
    float* __restrict__ out, char* __restrict__ ws)
{
  __shared__ __align__(16) char  ldsA[32768];   // A-frags: [L][hf][kt][lane]16B
  __shared__ __align__(16) f32x4 xch[8][64];    // L1 B->A partials

  const int tid  = threadIdx.x, lane = tid & 63, wv = tid >> 6;
  const int g    = blockIdx.x & 7;      // group (XCD-local M slice, proven r2)
  const int w    = blockIdx.x >> 3;     // 0..15: unit tile
  const int col16 = lane & 15, ko8 = (lane >> 4) << 3;
  const int unit = w * 16 + col16;
  const int hf   = wv & 1;              // batch half
  const int role = wv >> 1;             // 0:L0 1:L1A 2:L1B 3:stage-only

  // ring(g, L, slot) = ws + ((g*4 + L*2 + slot) << 14); 8*4*16KB = 512KB
  #define RING(L, slot) (ws + (((g << 2) + ((L) << 1) + (slot)) << 14))

  // ---- register-resident weights: 4 gates x 16 units ----
  f16x8 W0[4][8], WI[4];
  float bias[4] = {0.f, 0.f, 0.f, 0.f};
  if (role == 0) {
    #pragma unroll
    for (int q = 0; q < 4; ++q) {
      const int row = q * HH + unit;
      #pragma unroll
      for (int kt = 0; kt < 8; ++kt)
        W0[q][kt] = cvt8(Whh0 + (size_t)row * HH + kt * 32 + ko8);
      WI[q]   = cvt8(Wih0 + (size_t)row * 32 + ko8);
      bias[q] = bih0[row] + bhh0[row];
    }
  } else if (role == 1) {
    #pragma unroll
    for (int q = 0; q < 4; ++q) {
      const int row = q * HH + unit;
      #pragma unroll
      for (int kt = 0; kt < 8; ++kt)
        W0[q][kt] = cvt8(Wih1 + (size_t)row * HH + kt * 32 + ko8);
      bias[q] = bih1[row] + bhh1[row];
    }
  } else if (role == 2) {
    #pragma unroll
    for (int q = 0; q < 4; ++q) {
      const int row = q * HH + unit;
      #pragma unroll
      for (int kt = 0; kt < 8; ++kt)
        W0[q][kt] = cvt8(Whh1 + (size_t)row * HH + kt * 32 + ko8);
    }
  }

  // staging decode: thread -> frag (kt, l) for both halves, both layers
  const int sl  = tid & 63;
  const int skt = (tid >> 6) & 7;
  const unsigned moff0 = (unsigned)((sl & 15) * 512 + skt * 64 + (sl >> 4) * 16);
  const unsigned moff1 = moff0 + 16 * 512;
  const unsigned lo    = (unsigned)(skt * 1024 + sl * 16);

  // M prefetch (role 0): per-lane A-frag source, plain cached loads
  const float* mp = M + (size_t)(g * 32 + hf * 16 + col16) * TT * 32 + ko8;
  float4 m0 = {0,0,0,0}, m1 = {0,0,0,0};
  if (role == 0) { m0 = *(const float4*)mp; m1 = *(const float4*)(mp + 4); }

  float cst[4] = {0.f, 0.f, 0.f, 0.f};

  for (int p = 0; p <= TT; ++p) {
    // ---- stage h0[p-1], h1[p-2] into LDS A-frag layout, tag-spun ----
    {
      const char* s0 = RING(0, (p - 1) & 1);
      const char* s1 = RING(1, p & 1);            // (p-2)&1 == p&1
      const unsigned pat0 = tg(p - 1) * 0x00010001u;
      const unsigned pat1 = tg(p - 2) * 0x00010001u;
      u32x4 v00 = ld16_sv(moff0, s0), v01 = ld16_sv(moff1, s0);
      u32x4 v10 = ld16_sv(moff0, s1), v11 = ld16_sv(moff1, s1);
      wvm0();
      for (;;) {
        u32x4 d = (((v00 ^ pat0) | (v01 ^ pat0)) |
                   ((v10 ^ pat1) | (v11 ^ pat1))) & 0x00010001u;
        if (__all((d[0] | d[1] | d[2] | d[3]) == 0)) break;
        v00 = ld16_sv(moff0, s0); v01 = ld16_sv(moff1, s0);
        v10 = ld16_sv(moff0, s1); v11 = ld16_sv(moff1, s1);
        wvm0();
      }
      *(u32x4*)(ldsA + lo)         = v00;
      *(u32x4*)(ldsA + 8192 + lo)  = v01;
      *(u32x4*)(ldsA + 16384 + lo) = v10;
      *(u32x4*)(ldsA + 24576 + lo) = v11;
    }
    barrier_lds();

    // ---- compute ----
    f32x4 acc[4];
    if (role == 0 && p < TT) {
      f16x8 am;
      am[0]=(_Float16)m0.x; am[1]=(_Float16)m0.y; am[2]=(_Float16)m0.z; am[3]=(_Float16)m0.w;
      am[4]=(_Float16)m1.x; am[5]=(_Float16)m1.y; am[6]=(_Float16)m1.z; am[7]=(_Float16)m1.w;
      #pragma unroll
      for (int q = 0; q < 4; ++q) {
        acc[q] = (f32x4){bias[q], bias[q], bias[q], bias[q]};
        acc[q] = __builtin_amdgcn_mfma_f32_16x16x32_f16(am, WI[q], acc[q], 0, 0, 0);
      }
      #pragma unroll
      for (int kt = 0; kt < 8; ++kt) {
        const f16x8 A = *(const f16x8*)(ldsA + hf * 8192 + kt * 1024 + lane * 16);
        #pragma unroll
        for (int q = 0; q < 4; ++q)
          acc[q] = __builtin_amdgcn_mfma_f32_16x16x32_f16(A, W0[q][kt], acc[q], 0, 0, 0);
      }
      // elementwise + tagged h0[p] store (fire-and-forget)
      char* dst = RING(0, p & 1);
      const unsigned wt = tg(p);
      #pragma unroll
      for (int r = 0; r < 4; ++r) {
        const float iv = sigm(acc[0][r]), fv = sigm(acc[1][r]);
        const float gv = tanh_(acc[2][r]), ov = sigm(acc[3][r]);
        cst[r] = fv * cst[r] + iv * gv;
        const float h = ov * tanh_(cst[r]);
        unsigned short hb = __builtin_bit_cast(unsigned short, (_Float16)h);
        hb = (unsigned short)((hb & 0xFFFEu) | wt);
        const int b = hf * 16 + ((lane >> 4) << 2) + r;
        st2_sv((unsigned)(b * 512 + unit * 2), (unsigned)hb, dst);
      }
      if (p + 1 < TT) {                 // M prefetch for next phase
        m0 = *(const float4*)(mp + (p + 1) * 32);
        m1 = *(const float4*)(mp + (p + 1) * 32 + 4);
      }
    } else if ((role == 1 || role == 2) && p >= 1) {
      const int Lb = (role == 2) ? 16384 : 0;     // A source: h0 or h1
      #pragma unroll
      for (int q = 0; q < 4; ++q)
        acc[q] = (f32x4){bias[q], bias[q], bias[q], bias[q]};
      #pragma unroll
      for (int kt = 0; kt < 8; ++kt) {
        const f16x8 A = *(const f16x8*)(ldsA + Lb + hf * 8192 + kt * 1024 + lane * 16);
        #pragma unroll
        for (int q = 0; q < 4; ++q)
          acc[q] = __builtin_amdgcn_mfma_f32_16x16x32_f16(A, W0[q][kt], acc[q], 0, 0, 0);
      }
      if (role == 2) {
        #pragma unroll
        for (int q = 0; q < 4; ++q) xch[(hf << 2) + q][lane] = acc[q];
      }
    }
    barrier_lds();

    // ---- L1-A: merge partials, elementwise, h1[p-1] store / final out ----
    if (role == 1 && p >= 1) {
      #pragma unroll
      for (int q = 0; q < 4; ++q) acc[q] = acc[q] + xch[(hf << 2) + q][lane];
      char* dst = RING(1, (p - 1) & 1);
      const unsigned wt = tg(p - 1);
      #pragma unroll
      for (int r = 0; r < 4; ++r) {
        const float iv = sigm(acc[0][r]), fv = sigm(acc[1][r]);
        const float gv = tanh_(acc[2][r]), ov = sigm(acc[3][r]);
        cst[r] = fv * cst[r] + iv * gv;
        const float h = ov * tanh_(cst[r]);
        const int b = hf * 16 + ((lane >> 4) << 2) + r;
        if (p < TT) {
          unsigned short hb = __builtin_bit_cast(unsigned short, (_Float16)h);
          hb = (unsigned short)((hb & 0xFFFEu) | wt);
          st2_sv((unsigned)(b * 512 + unit * 2), (unsigned)hb, dst);
        } else {
          out[(size_t)(g * 32 + b) * HH + unit] = h;   // final h1[T-1], fp32
        }
      }
    }
  }
  #undef RING
}

extern "C" void kernel_launch(void* const* d_in, const int* in_sizes, int n_in,
                              void* d_out, int out_size, void* d_ws, size_t ws_size,
                              hipStream_t stream) {
  (void)in_sizes; (void)n_in; (void)out_size;
  if (ws_size < 524288) return;   // 8 groups x 2 layers x 2 slots x 16KB

  const float* M    = (const float*)d_in[0];
  const float* Wih0 = (const float*)d_in[1];
  const float* Whh0 = (const float*)d_in[2];
  const float* bih0 = (const float*)d_in[3];
  const float* bhh0 = (const float*)d_in[4];
  const float* Wih1 = (const float*)d_in[5];
  const float* Whh1 = (const float*)d_in[6];
  const float* bih1 = (const float*)d_in[7];
  const float* bhh1 = (const float*)d_in[8];

  init_ws<<<128, 256, 0, stream>>>((uint4*)d_ws, 32768);
  lstm_pipe<<<128, 512, 0, stream>>>(M, Wih0, Whh0, bih0, bhh0,
                                     Wih1, Whh1, bih1, bhh1,
                                     (float*)d_out, (char*)d_ws);
}